// Round 6
// baseline (502.019 us; speedup 1.0000x reference)
//
#include <hip/hip_runtime.h>
#include <math.h>

#define HID 16
typedef unsigned int uint;

#define PSHIFT 7            // 128 nodes per dst-bucket
#define PSIZE  128
#define PMASK  127
#define SRCBITS 17          // supports N <= 131072
#define SRCMASK 0x1FFFFu
#define PAD 16              // uints between atomic counters (64B anti-contention)
#define TILE 8192           // edges per partition tile
#define NSTRIP 2            // src strips (each strip's g-slice fits 4MB XCD L2)
#define MAXBINS 2048        // NSTRIP * max dst-buckets (N<=131072 -> 1024*2)
#define AGT 1024            // threads for aggregation kernels

// ============================= fast path: (srcStrip, dstBucket) multisplit =============================

// ---- pass 1: per-bin edge counts ----
__global__ void p_bcount(const int* __restrict__ srcA, const int* __restrict__ dstA,
                         uint* __restrict__ cntPad, int e, int nb, int halfN) {
    __shared__ uint hist[MAXBINS];
    int t = threadIdx.x;
    int nbins = nb * NSTRIP;
    for (int i = t; i < nbins; i += 256) hist[i] = 0;
    __syncthreads();
    int base = blockIdx.x * TILE;
#pragma unroll
    for (int k = 0; k < TILE / 256; ++k) {
        int idx = base + k * 256 + t;
        if (idx < e) {
            uint d = (uint)dstA[idx];
            uint s = (uint)srcA[idx];
            uint bin = ((s >= (uint)halfN) ? (uint)nb : 0u) + (d >> PSHIFT);
            atomicAdd(&hist[bin], 1u);
        }
    }
    __syncthreads();
    for (int i = t; i < nbins; i += 256) {
        uint c = hist[i];
        if (c) atomicAdd(&cntPad[i * PAD], c);
    }
}

// ---- pass 2: exclusive scan of bin counts; init global cursors ----
__global__ void p_bscan(const uint* __restrict__ cntPad, uint* __restrict__ cursorPad,
                        uint* __restrict__ bBase, uint* __restrict__ bCnt, int nbins) {
    __shared__ uint tsum[256];
    int t = threadIdx.x;
    uint loc[8]; uint s = 0;
#pragma unroll
    for (int k = 0; k < 8; ++k) {
        int i = t * 8 + k;
        uint c = (i < nbins) ? cntPad[i * PAD] : 0u;
        loc[k] = s; s += c;
    }
    tsum[t] = s;
    __syncthreads();
    for (int off = 1; off < 256; off <<= 1) {
        uint v = (t >= off) ? tsum[t - off] : 0u;
        __syncthreads();
        tsum[t] += v;
        __syncthreads();
    }
    uint excl = (t == 0) ? 0u : tsum[t - 1];
#pragma unroll
    for (int k = 0; k < 8; ++k) {
        int i = t * 8 + k;
        if (i < nbins) {
            uint c = cntPad[i * PAD];
            uint b = excl + loc[k];
            bBase[i] = b; bCnt[i] = c; cursorPad[i * PAD] = b;
        }
    }
}

// ---- pass 3: partition edges into (strip,bucket) bins (LDS multisplit per tile) ----
__global__ void p_part(const int* __restrict__ srcA, const int* __restrict__ dstA,
                       uint* __restrict__ cursorPad, uint* __restrict__ part,
                       int e, int nb, int halfN) {
    __shared__ uint payload[TILE];      // 32 KB
    __shared__ uint hist[MAXBINS];      // 8 KB
    __shared__ uint cursorL[MAXBINS];   // 8 KB
    __shared__ uint gdelta[MAXBINS];    // 8 KB
    __shared__ uint tsum[256];          // 1 KB  (~57 KB total)
    int t = threadIdx.x;
    int nbins = nb * NSTRIP;
    for (int i = t; i < nbins; i += 256) hist[i] = 0;
    __syncthreads();
    int base = blockIdx.x * TILE;
    // phase A: tile histogram over (strip,bucket)
#pragma unroll
    for (int k = 0; k < TILE / 256; ++k) {
        int idx = base + k * 256 + t;
        if (idx < e) {
            uint d = (uint)dstA[idx];
            uint s = (uint)srcA[idx];
            uint bin = ((s >= (uint)halfN) ? (uint)nb : 0u) + (d >> PSHIFT);
            atomicAdd(&hist[bin], 1u);
        }
    }
    __syncthreads();
    // phase B: scan -> local bin starts; reserve global space per bin
    uint loc[8]; uint s = 0;
#pragma unroll
    for (int k = 0; k < 8; ++k) {
        int i = t * 8 + k;
        uint c = (i < nbins) ? hist[i] : 0u;
        loc[k] = s; s += c;
    }
    tsum[t] = s;
    __syncthreads();
    for (int off = 1; off < 256; off <<= 1) {
        uint v = (t >= off) ? tsum[t - off] : 0u;
        __syncthreads();
        tsum[t] += v;
        __syncthreads();
    }
    uint excl = (t == 0) ? 0u : tsum[t - 1];
#pragma unroll
    for (int k = 0; k < 8; ++k) {
        int i = t * 8 + k;
        if (i < nbins) {
            uint bs = excl + loc[k];
            cursorL[i] = bs;
            uint c = hist[i];
            if (c) gdelta[i] = atomicAdd(&cursorPad[i * PAD], c) - bs;
        }
    }
    __syncthreads();
    // phase C: scatter packed words into LDS, grouped by bin
#pragma unroll
    for (int k = 0; k < TILE / 256; ++k) {
        int idx = base + k * 256 + t;
        if (idx < e) {
            uint d = (uint)dstA[idx];
            uint sv = (uint)srcA[idx];
            uint w = ((d & PMASK) << SRCBITS) | sv;
            uint bin = ((sv >= (uint)halfN) ? (uint)nb : 0u) + (d >> PSHIFT);
            uint pos = atomicAdd(&cursorL[bin], 1u);
            payload[pos] = w;
        }
    }
    __syncthreads();
    // phase D: flush contiguous runs to global (16-lane groups per run)
    int grp = t >> 4, lane16 = t & 15;
    for (int bk = grp; bk < nbins; bk += 16) {
        uint c = hist[bk];
        if (!c) continue;
        uint st = cursorL[bk] - c;      // cursorL ended at start + c
        uint gd = gdelta[bk];
        for (uint i = lane16; i < c; i += 16)
            part[gd + st + i] = payload[st + i];
    }
}

// ---- pass 4: per-bucket degree (both strips) -> dinv, y = x*dinv ----
__global__ __launch_bounds__(AGT)
void p_degy(const uint* __restrict__ part, const uint* __restrict__ bBase,
            const uint* __restrict__ bCnt, const float* __restrict__ x,
            float* __restrict__ dinv, float* __restrict__ y, int n, int nb) {
    __shared__ uint cnts[PSIZE];
    int b = blockIdx.x, t = threadIdx.x;
    if (t < PSIZE) cnts[t] = 0;
    __syncthreads();
#pragma unroll
    for (int sp = 0; sp < NSTRIP; ++sp) {
        int bin = sp * nb + b;
        uint base = bBase[bin], cnt = bCnt[bin];
        for (uint i = base + t; i < base + cnt; i += AGT)
            atomicAdd(&cnts[part[i] >> SRCBITS], 1u);
    }
    __syncthreads();
    if (t < PSIZE) {
        int node = b * PSIZE + t;
        if (node < n) {
            float d = rsqrtf((float)(cnts[t] + 1u));   // +1 self-loop
            dinv[node] = d;
            y[node] = x[node] * d;
        }
    }
}

// ---- pass 5: layer-1 aggregate (both strips) + fused MLP -> g ----
__global__ __launch_bounds__(AGT)
void p_agg1(const uint* __restrict__ part, const uint* __restrict__ bBase,
            const uint* __restrict__ bCnt, const float* __restrict__ y,
            const float* __restrict__ dinv,
            const float* __restrict__ W1, const float* __restrict__ b1,
            const float* __restrict__ W2,
            float* __restrict__ g, int n, int nb) {
    __shared__ float acc[PSIZE];
    int b = blockIdx.x, t = threadIdx.x;
    if (t < PSIZE) acc[t] = 0.0f;
    __syncthreads();
#pragma unroll
    for (int sp = 0; sp < NSTRIP; ++sp) {
        int bin = sp * nb + b;
        uint base = bBase[bin], cnt = bCnt[bin];
        for (uint i = base + t; i < base + cnt; i += AGT) {
            uint w = part[i];
            atomicAdd(&acc[w >> SRCBITS], y[w & SRCMASK]);
        }
    }
    __syncthreads();
    if (t < PSIZE) {
        int node = b * PSIZE + t;
        if (node < n) {
            float d = dinv[node];
            float sv = d * (acc[t] + y[node]);   // self-loop: x*dinv^2 = dinv*y
            float h1[HID], h2[HID];
#pragma unroll
            for (int j = 0; j < HID; ++j)
                h1[j] = fmaxf(sv * W1[j] + b1[j], 0.0f);
#pragma unroll
            for (int k = 0; k < HID; ++k) {
                float a = 0.0f;
#pragma unroll
                for (int j = 0; j < HID; ++j)
                    a = fmaf(h1[j], W2[j * HID + k], a);
                h2[k] = a * d;
            }
            float4* gp = (float4*)(g + (size_t)node * HID);
#pragma unroll
            for (int q = 0; q < 4; ++q)
                gp[q] = make_float4(h2[q*4+0], h2[q*4+1], h2[q*4+2], h2[q*4+3]);
        }
    }
}

// ---- pass 6: layer-2 aggregate, strip-by-strip (L2-resident g slice) + epilogue ----
__global__ __launch_bounds__(AGT)
void p_agg2(const uint* __restrict__ part, const uint* __restrict__ bBase,
            const uint* __restrict__ bCnt, const float* __restrict__ g,
            const float* __restrict__ dinv,
            const float* __restrict__ b2, const float* __restrict__ Wf,
            const float* __restrict__ bf,
            float* __restrict__ out, int n, int nb) {
    __shared__ float acc[PSIZE][HID + 1];   // +1 pad: breaks bank conflicts
    int b = blockIdx.x, t = threadIdx.x;
    // init: self-loop contribution g[node]; 512 threads, float4 each
    if (t < PSIZE * 4) {
        int r = t >> 2, q = t & 3;
        int node = b * PSIZE + r;
        if (node < n) {
            float4 v = *(const float4*)(g + (size_t)node * HID + 4 * q);
            acc[r][q*4+0] = v.x; acc[r][q*4+1] = v.y;
            acc[r][q*4+2] = v.z; acc[r][q*4+3] = v.w;
        } else {
            acc[r][q*4+0] = 0.0f; acc[r][q*4+1] = 0.0f;
            acc[r][q*4+2] = 0.0f; acc[r][q*4+3] = 0.0f;
        }
    }
    __syncthreads();
    int gi = t >> 2;        // 256 edge-groups of 4 lanes
    int sub = t & 3;        // this lane's float4 slot within the row
#pragma unroll
    for (int sp = 0; sp < NSTRIP; ++sp) {
        int bin = sp * nb + b;
        uint base = bBase[bin], cnt = bCnt[bin];
        for (uint i = base + gi; i < base + cnt; i += AGT / 4) {
            uint w = part[i];                    // broadcast within 4-lane group
            uint src = w & SRCMASK;
            uint dl = w >> SRCBITS;
            float4 v = *(const float4*)(g + (size_t)src * HID + 4 * sub);  // L2-resident slice
            atomicAdd(&acc[dl][sub*4+0], v.x);
            atomicAdd(&acc[dl][sub*4+1], v.y);
            atomicAdd(&acc[dl][sub*4+2], v.z);
            atomicAdd(&acc[dl][sub*4+3], v.w);
        }
    }
    __syncthreads();
    if (t < PSIZE) {
        int node = b * PSIZE + t;
        if (node < n) {
            float d = dinv[node];
            float o = bf[0];
#pragma unroll
            for (int j = 0; j < HID; ++j) {
                float h = fmaxf(fmaf(d, acc[t][j], b2[j]), 0.0f);
                o = fmaf(h, Wf[j], o);
            }
            out[node] = tanhf(o);
        }
    }
}

// ============================= fallback (atomic) path =============================

__global__ void f_init_deg(float* deg, int n) {
    int i = blockIdx.x * blockDim.x + threadIdx.x;
    if (i < n) deg[i] = 1.0f;
}

__global__ void f_deg_accum(const int* __restrict__ dstA, float* deg, int e) {
    int i = blockIdx.x * blockDim.x + threadIdx.x;
    if (i < e) atomicAdd(&deg[dstA[i]], 1.0f);
}

__global__ void f_dinv_s(const float* __restrict__ x, float* deg_dinv, float* s, int n) {
    int i = blockIdx.x * blockDim.x + threadIdx.x;
    if (i < n) {
        float d = rsqrtf(deg_dinv[i]);
        deg_dinv[i] = d;
        s[i] = x[i] * d * d;
    }
}

__global__ void f_s_edge(const int* __restrict__ srcA, const int* __restrict__ dstA,
                         const float* __restrict__ x, const float* __restrict__ dinv,
                         float* s, int e) {
    int i = blockIdx.x * blockDim.x + threadIdx.x;
    if (i < e) {
        int si = srcA[i], di = dstA[i];
        atomicAdd(&s[di], x[si] * dinv[si] * dinv[di]);
    }
}

__global__ void f_node_mlp(const float* __restrict__ s, const float* __restrict__ dinv,
                           const float* __restrict__ W1, const float* __restrict__ b1,
                           const float* __restrict__ W2,
                           float* __restrict__ h2pre, float* __restrict__ agg2, int n) {
    int i = blockIdx.x * blockDim.x + threadIdx.x;
    if (i >= n) return;
    float sv = s[i];
    float h1[HID];
#pragma unroll
    for (int j = 0; j < HID; ++j)
        h1[j] = fmaxf(sv * W1[j] + b1[j], 0.0f);
    float d2 = dinv[i] * dinv[i];
    float h2[HID];
#pragma unroll
    for (int k = 0; k < HID; ++k) {
        float acc = 0.0f;
#pragma unroll
        for (int j = 0; j < HID; ++j)
            acc = fmaf(h1[j], W2[j * HID + k], acc);
        h2[k] = acc;
    }
    float4* hp = (float4*)(h2pre + (size_t)i * HID);
    float4* ap = (float4*)(agg2 + (size_t)i * HID);
#pragma unroll
    for (int q = 0; q < 4; ++q) {
        float4 v = make_float4(h2[q*4+0], h2[q*4+1], h2[q*4+2], h2[q*4+3]);
        hp[q] = v;
        ap[q] = make_float4(v.x * d2, v.y * d2, v.z * d2, v.w * d2);
    }
}

__global__ void f_agg_edge(const int* __restrict__ srcA, const int* __restrict__ dstA,
                           const float* __restrict__ dinv,
                           const float* __restrict__ h2pre,
                           float* __restrict__ agg2, int e) {
    int gid = blockIdx.x * blockDim.x + threadIdx.x;
    int ei = gid >> 4;
    int j  = gid & 15;
    if (ei < e) {
        int si = srcA[ei], di = dstA[ei];
        float w = dinv[si] * dinv[di];
        atomicAdd(&agg2[(size_t)di * HID + j], h2pre[(size_t)si * HID + j] * w);
    }
}

__global__ void f_out(const float* __restrict__ agg2, const float* __restrict__ b2,
                      const float* __restrict__ Wf, const float* __restrict__ bf,
                      float* __restrict__ out, int n) {
    int i = blockIdx.x * blockDim.x + threadIdx.x;
    if (i >= n) return;
    float acc = bf[0];
#pragma unroll
    for (int k = 0; k < HID; ++k) {
        float h = fmaxf(agg2[(size_t)i * HID + k] + b2[k], 0.0f);
        acc = fmaf(h, Wf[k], acc);
    }
    out[i] = tanhf(acc);
}

// ============================= launch =============================

extern "C" void kernel_launch(void* const* d_in, const int* in_sizes, int n_in,
                              void* d_out, int out_size, void* d_ws, size_t ws_size,
                              hipStream_t stream) {
    const float* x  = (const float*)d_in[0];
    const int*   ei = (const int*)d_in[1];
    const float* W1 = (const float*)d_in[2];
    const float* b1 = (const float*)d_in[3];
    const float* W2 = (const float*)d_in[4];
    const float* b2 = (const float*)d_in[5];
    const float* Wf = (const float*)d_in[6];
    const float* bf = (const float*)d_in[7];
    float* out = (float*)d_out;

    const int N = in_sizes[0];
    const int E = in_sizes[1] / 2;
    const int* srcA = ei;
    const int* dstA = ei + E;
    (void)n_in; (void)out_size;

    const int NB = (N + PMASK) >> PSHIFT;
    const int NBINS = NB * NSTRIP;
    const int halfN = (N + 1) / 2;
    const int B = 256;
    int nb_n = (N + B - 1) / B;
    int nb_e = (E + B - 1) / B;
    int tiles = (E + TILE - 1) / TILE;

    // fast-path ws layout
    size_t off = 0;
    auto takeo = [&](size_t bytes) -> size_t {
        size_t p = off;
        off = (off + bytes + 255) & ~(size_t)255;
        return p;
    };
    size_t o_cntp = takeo((size_t)NBINS * PAD * 4);
    size_t o_curp = takeo((size_t)NBINS * PAD * 4);
    size_t o_bb   = takeo((size_t)NBINS * 4);
    size_t o_bc   = takeo((size_t)NBINS * 4);
    size_t o_dinv = takeo((size_t)N * 4);
    size_t o_y    = takeo((size_t)N * 4);
    size_t o_part = takeo((size_t)E * 4);
    size_t o_g    = takeo((size_t)N * HID * 4);
    size_t need = off;

    if (N <= (1 << SRCBITS) && NBINS <= MAXBINS && ws_size >= need) {
        char* ws = (char*)d_ws;
        uint*  cntPad    = (uint*)(ws + o_cntp);
        uint*  cursorPad = (uint*)(ws + o_curp);
        uint*  bBase     = (uint*)(ws + o_bb);
        uint*  bCnt      = (uint*)(ws + o_bc);
        float* dinv      = (float*)(ws + o_dinv);
        float* y         = (float*)(ws + o_y);
        uint*  part      = (uint*)(ws + o_part);
        float* g         = (float*)(ws + o_g);

        hipMemsetAsync(cntPad, 0, (size_t)NBINS * PAD * 4, stream);
        hipLaunchKernelGGL(p_bcount, dim3(tiles), dim3(B), 0, stream, srcA, dstA, cntPad, E, NB, halfN);
        hipLaunchKernelGGL(p_bscan,  dim3(1), dim3(B), 0, stream, cntPad, cursorPad, bBase, bCnt, NBINS);
        hipLaunchKernelGGL(p_part,   dim3(tiles), dim3(B), 0, stream, srcA, dstA, cursorPad, part, E, NB, halfN);
        hipLaunchKernelGGL(p_degy,   dim3(NB), dim3(AGT), 0, stream, part, bBase, bCnt, x, dinv, y, N, NB);
        hipLaunchKernelGGL(p_agg1,   dim3(NB), dim3(AGT), 0, stream, part, bBase, bCnt, y, dinv, W1, b1, W2, g, N, NB);
        hipLaunchKernelGGL(p_agg2,   dim3(NB), dim3(AGT), 0, stream, part, bBase, bCnt, g, dinv, b2, Wf, bf, out, N, NB);
    } else {
        // fallback: known-good atomic path
        size_t foff = 0;
        auto ftake = [&](size_t bytes) -> size_t {
            size_t p = foff;
            foff = (foff + bytes + 255) & ~(size_t)255;
            return p;
        };
        char* ws = (char*)d_ws;
        float* dinv  = (float*)(ws + ftake((size_t)N * 4));
        float* s     = (float*)(ws + ftake((size_t)N * 4));
        float* h2pre = (float*)(ws + ftake((size_t)N * HID * 4));
        float* agg2  = (float*)(ws + ftake((size_t)N * HID * 4));

        long long totD = (long long)E * HID;
        int nb_d = (int)((totD + B - 1) / B);

        hipLaunchKernelGGL(f_init_deg,  dim3(nb_n), dim3(B), 0, stream, dinv, N);
        hipLaunchKernelGGL(f_deg_accum, dim3(nb_e), dim3(B), 0, stream, dstA, dinv, E);
        hipLaunchKernelGGL(f_dinv_s,    dim3(nb_n), dim3(B), 0, stream, x, dinv, s, N);
        hipLaunchKernelGGL(f_s_edge,    dim3(nb_e), dim3(B), 0, stream, srcA, dstA, x, dinv, s, E);
        hipLaunchKernelGGL(f_node_mlp,  dim3(nb_n), dim3(B), 0, stream,
                           s, dinv, W1, b1, W2, h2pre, agg2, N);
        hipLaunchKernelGGL(f_agg_edge,  dim3(nb_d), dim3(B), 0, stream,
                           srcA, dstA, dinv, h2pre, agg2, E);
        hipLaunchKernelGGL(f_out,       dim3(nb_n), dim3(B), 0, stream,
                           agg2, b2, Wf, bf, out, N);
    }
}

// Round 7
// 157.149 us; speedup vs baseline: 3.1945x; 3.1945x over previous
//
#include <hip/hip_runtime.h>
#include <math.h>

#define HID 16
typedef unsigned int uint;

#define PSHIFT 7            // 128 nodes per dst-bucket
#define PSIZE  128
#define PMASK  127
#define SRCBITS 17          // supports N <= 131072
#define SRCMASK 0x1FFFFu
#define PAD 16              // uints between atomic counters (64B anti-contention)
#define TILE 8192           // edges per partition tile
#define MAXNB 1024          // max dst-buckets (N<=131072)
#define AGT 1024            // threads for aggregation kernels
#define CAP 6144            // max edges per bucket for sorted path (avg ~4096)

// ============================= fast path =============================

// ---- pass 1: per-bucket edge counts ----
__global__ void p_bcount(const int* __restrict__ dstA, uint* __restrict__ cntPad,
                         int e, int nb) {
    __shared__ uint hist[MAXNB];
    int t = threadIdx.x;
    for (int i = t; i < nb; i += 256) hist[i] = 0;
    __syncthreads();
    int base = blockIdx.x * TILE;
#pragma unroll
    for (int k = 0; k < TILE / 256; ++k) {
        int idx = base + k * 256 + t;
        if (idx < e) atomicAdd(&hist[((uint)dstA[idx]) >> PSHIFT], 1u);
    }
    __syncthreads();
    for (int i = t; i < nb; i += 256) {
        uint c = hist[i];
        if (c) atomicAdd(&cntPad[i * PAD], c);
    }
}

// ---- pass 2: exclusive scan of bucket counts; init global cursors ----
__global__ void p_bscan(const uint* __restrict__ cntPad, uint* __restrict__ cursorPad,
                        uint* __restrict__ bBase, uint* __restrict__ bCnt, int nb) {
    __shared__ uint tsum[256];
    int t = threadIdx.x;
    uint loc[4]; uint s = 0;
#pragma unroll
    for (int k = 0; k < 4; ++k) {
        int i = t * 4 + k;
        uint c = (i < nb) ? cntPad[i * PAD] : 0u;
        loc[k] = s; s += c;
    }
    tsum[t] = s;
    __syncthreads();
    for (int off = 1; off < 256; off <<= 1) {
        uint v = (t >= off) ? tsum[t - off] : 0u;
        __syncthreads();
        tsum[t] += v;
        __syncthreads();
    }
    uint excl = (t == 0) ? 0u : tsum[t - 1];
#pragma unroll
    for (int k = 0; k < 4; ++k) {
        int i = t * 4 + k;
        if (i < nb) {
            uint c = cntPad[i * PAD];
            uint b = excl + loc[k];
            bBase[i] = b; bCnt[i] = c; cursorPad[i * PAD] = b;
        }
    }
}

// ---- pass 3: partition edges into dst-buckets (LDS multisplit per tile) ----
__global__ void p_part(const int* __restrict__ srcA, const int* __restrict__ dstA,
                       uint* __restrict__ cursorPad, uint* __restrict__ part,
                       int e, int nb) {
    __shared__ uint payload[TILE];      // 32 KB
    __shared__ uint hist[MAXNB];
    __shared__ uint binStart[MAXNB];
    __shared__ uint cursorL[MAXNB];
    __shared__ uint gdelta[MAXNB];
    __shared__ uint tsum[256];
    int t = threadIdx.x;
    for (int i = t; i < nb; i += 256) hist[i] = 0;
    __syncthreads();
    int base = blockIdx.x * TILE;
#pragma unroll
    for (int k = 0; k < TILE / 256; ++k) {
        int idx = base + k * 256 + t;
        if (idx < e) atomicAdd(&hist[((uint)dstA[idx]) >> PSHIFT], 1u);
    }
    __syncthreads();
    uint loc[4]; uint s = 0;
#pragma unroll
    for (int k = 0; k < 4; ++k) {
        int i = t * 4 + k;
        uint c = (i < nb) ? hist[i] : 0u;
        loc[k] = s; s += c;
    }
    tsum[t] = s;
    __syncthreads();
    for (int off = 1; off < 256; off <<= 1) {
        uint v = (t >= off) ? tsum[t - off] : 0u;
        __syncthreads();
        tsum[t] += v;
        __syncthreads();
    }
    uint excl = (t == 0) ? 0u : tsum[t - 1];
#pragma unroll
    for (int k = 0; k < 4; ++k) {
        int i = t * 4 + k;
        if (i < nb) {
            uint bs = excl + loc[k];
            binStart[i] = bs; cursorL[i] = bs;
            uint c = hist[i];
            if (c) gdelta[i] = atomicAdd(&cursorPad[i * PAD], c) - bs;
        }
    }
    __syncthreads();
#pragma unroll
    for (int k = 0; k < TILE / 256; ++k) {
        int idx = base + k * 256 + t;
        if (idx < e) {
            uint d = (uint)dstA[idx];
            uint w = ((d & PMASK) << SRCBITS) | (uint)srcA[idx];
            uint bk = d >> PSHIFT;
            uint pos = atomicAdd(&cursorL[bk], 1u);
            payload[pos] = w;
        }
    }
    __syncthreads();
    int grp = t >> 4, lane16 = t & 15;
    for (int bk = grp; bk < nb; bk += 16) {
        uint c = hist[bk];
        if (!c) continue;
        uint st = binStart[bk];
        uint gd = gdelta[bk];
        for (uint i = lane16; i < c; i += 16)
            part[gd + st + i] = payload[st + i];
    }
}

// ---- pass 4: per-bucket degree -> dinv, y = x*dinv ----
__global__ __launch_bounds__(AGT)
void p_degy(const uint* __restrict__ part, const uint* __restrict__ bBase,
            const uint* __restrict__ bCnt, const float* __restrict__ x,
            float* __restrict__ dinv, float* __restrict__ y, int n) {
    __shared__ uint cnts[PSIZE];
    int b = blockIdx.x, t = threadIdx.x;
    if (t < PSIZE) cnts[t] = 0;
    __syncthreads();
    uint base = bBase[b], cnt = bCnt[b];
    for (uint i = base + t; i < base + cnt; i += AGT)
        atomicAdd(&cnts[part[i] >> SRCBITS], 1u);
    __syncthreads();
    if (t < PSIZE) {
        int node = b * PSIZE + t;
        if (node < n) {
            float d = rsqrtf((float)(cnts[t] + 1u));   // +1 self-loop
            dinv[node] = d;
            y[node] = x[node] * d;
        }
    }
}

// ---- pass 5: layer-1 aggregate + fused MLP -> g = (relu(s*W1+b1)@W2)*dinv ----
__global__ __launch_bounds__(AGT)
void p_agg1(const uint* __restrict__ part, const uint* __restrict__ bBase,
            const uint* __restrict__ bCnt, const float* __restrict__ y,
            const float* __restrict__ dinv,
            const float* __restrict__ W1, const float* __restrict__ b1,
            const float* __restrict__ W2,
            float* __restrict__ g, int n) {
    __shared__ float acc[PSIZE];
    int b = blockIdx.x, t = threadIdx.x;
    if (t < PSIZE) acc[t] = 0.0f;
    __syncthreads();
    uint base = bBase[b], cnt = bCnt[b];
    for (uint i = base + t; i < base + cnt; i += AGT) {
        uint w = part[i];
        atomicAdd(&acc[w >> SRCBITS], y[w & SRCMASK]);
    }
    __syncthreads();
    if (t < PSIZE) {
        int node = b * PSIZE + t;
        if (node < n) {
            float d = dinv[node];
            float sv = d * (acc[t] + y[node]);   // self-loop: x*dinv^2 = dinv*y
            float h1[HID], h2[HID];
#pragma unroll
            for (int j = 0; j < HID; ++j)
                h1[j] = fmaxf(sv * W1[j] + b1[j], 0.0f);
#pragma unroll
            for (int k = 0; k < HID; ++k) {
                float a = 0.0f;
#pragma unroll
                for (int j = 0; j < HID; ++j)
                    a = fmaf(h1[j], W2[j * HID + k], a);
                h2[k] = a * d;
            }
            float4* gp = (float4*)(g + (size_t)node * HID);
#pragma unroll
            for (int q = 0; q < 4; ++q)
                gp[q] = make_float4(h2[q*4+0], h2[q*4+1], h2[q*4+2], h2[q*4+3]);
        }
    }
}

// ---- pass 6: in-LDS counting sort per bucket, then per-node register-accumulated
//      segment gather (16 lanes/node) + fused epilogue ----
__global__ __launch_bounds__(AGT)
void p_sagg2(const uint* __restrict__ part, const uint* __restrict__ bBase,
             const uint* __restrict__ bCnt, const float* __restrict__ g,
             const float* __restrict__ dinv,
             const float* __restrict__ b2, const float* __restrict__ Wf,
             const float* __restrict__ bf,
             float* __restrict__ out, int n) {
    __shared__ uint staged[CAP];        // 24 KB
    __shared__ uint sorted[CAP];        // 24 KB
    __shared__ uint hist[PSIZE];        // counts -> inclusive prefix (rowEnd)
    __shared__ uint cursor[PSIZE];
    int b = blockIdx.x, t = threadIdx.x;
    uint base = bBase[b], cnt = bCnt[b];
    if (t < PSIZE) hist[t] = 0;
    __syncthreads();

    if (cnt <= CAP) {
        // stage + per-dst count
        for (uint i = t; i < cnt; i += AGT) {
            uint w = part[base + i];
            staged[i] = w;
            atomicAdd(&hist[w >> SRCBITS], 1u);
        }
        __syncthreads();
        uint myc = (t < PSIZE) ? hist[t] : 0u;
        // inclusive Hillis-Steele scan over 128 bins
        for (int off = 1; off < PSIZE; off <<= 1) {
            uint v = 0;
            if (t < PSIZE && t >= off) v = hist[t - off];
            __syncthreads();
            if (t < PSIZE) hist[t] += v;
            __syncthreads();
        }
        if (t < PSIZE) cursor[t] = hist[t] - myc;   // exclusive start
        __syncthreads();
        // scatter to sorted order (src only)
        for (uint i = t; i < cnt; i += AGT) {
            uint w = staged[i];
            uint pos = atomicAdd(&cursor[w >> SRCBITS], 1u);
            sorted[pos] = w & SRCMASK;
        }
        __syncthreads();
        // gather: 64 nodes per half, 16 lanes each, register accumulation
        int lane = t & 15;
#pragma unroll
        for (int half = 0; half < 2; ++half) {
            int nl = half * 64 + (t >> 4);
            int node = b * PSIZE + nl;
            uint en = hist[nl];
            uint st = (nl == 0) ? 0u : hist[nl - 1];
            float a = 0.0f;
            uint e = st;
            for (; e + 2 <= en; e += 2) {
                uint s0 = sorted[e], s1 = sorted[e + 1];
                a += g[(size_t)s0 * HID + lane] + g[(size_t)s1 * HID + lane];
            }
            if (e < en) a += g[(size_t)sorted[e] * HID + lane];
            if (node < n) {
                float d = dinv[node];
                float h = fmaxf(d * (a + g[(size_t)node * HID + lane]) + b2[lane], 0.0f);
                float v = h * Wf[lane];
#pragma unroll
                for (int m = 8; m >= 1; m >>= 1)
                    v += __shfl_xor(v, m, 16);
                if (lane == 0) out[node] = tanhf(v + bf[0]);
            }
        }
    } else {
        // oversize bucket fallback: LDS float accumulators (round-5 style)
        float* acc = (float*)staged;     // [PSIZE][HID+1] = 8704 B < 24 KB
        if (t < PSIZE * 4) {
            int r = t >> 2, q = t & 3;
            int node = b * PSIZE + r;
            if (node < n) {
                float4 v = *(const float4*)(g + (size_t)node * HID + 4 * q);
                acc[r * 17 + q*4+0] = v.x; acc[r * 17 + q*4+1] = v.y;
                acc[r * 17 + q*4+2] = v.z; acc[r * 17 + q*4+3] = v.w;
            } else {
                acc[r * 17 + q*4+0] = 0.0f; acc[r * 17 + q*4+1] = 0.0f;
                acc[r * 17 + q*4+2] = 0.0f; acc[r * 17 + q*4+3] = 0.0f;
            }
        }
        __syncthreads();
        int gi = t >> 2, sub = t & 3;
        for (uint i = base + gi; i < base + cnt; i += AGT / 4) {
            uint w = part[i];
            uint src = w & SRCMASK;
            uint dl = w >> SRCBITS;
            float4 v = *(const float4*)(g + (size_t)src * HID + 4 * sub);
            atomicAdd(&acc[dl * 17 + sub*4+0], v.x);
            atomicAdd(&acc[dl * 17 + sub*4+1], v.y);
            atomicAdd(&acc[dl * 17 + sub*4+2], v.z);
            atomicAdd(&acc[dl * 17 + sub*4+3], v.w);
        }
        __syncthreads();
        if (t < PSIZE) {
            int node = b * PSIZE + t;
            if (node < n) {
                float d = dinv[node];
                float o = bf[0];
#pragma unroll
                for (int j = 0; j < HID; ++j) {
                    float h = fmaxf(fmaf(d, acc[t * 17 + j], b2[j]), 0.0f);
                    o = fmaf(h, Wf[j], o);
                }
                out[node] = tanhf(o);
            }
        }
    }
}

// ============================= fallback (atomic) path =============================

__global__ void f_init_deg(float* deg, int n) {
    int i = blockIdx.x * blockDim.x + threadIdx.x;
    if (i < n) deg[i] = 1.0f;
}

__global__ void f_deg_accum(const int* __restrict__ dstA, float* deg, int e) {
    int i = blockIdx.x * blockDim.x + threadIdx.x;
    if (i < e) atomicAdd(&deg[dstA[i]], 1.0f);
}

__global__ void f_dinv_s(const float* __restrict__ x, float* deg_dinv, float* s, int n) {
    int i = blockIdx.x * blockDim.x + threadIdx.x;
    if (i < n) {
        float d = rsqrtf(deg_dinv[i]);
        deg_dinv[i] = d;
        s[i] = x[i] * d * d;
    }
}

__global__ void f_s_edge(const int* __restrict__ srcA, const int* __restrict__ dstA,
                         const float* __restrict__ x, const float* __restrict__ dinv,
                         float* s, int e) {
    int i = blockIdx.x * blockDim.x + threadIdx.x;
    if (i < e) {
        int si = srcA[i], di = dstA[i];
        atomicAdd(&s[di], x[si] * dinv[si] * dinv[di]);
    }
}

__global__ void f_node_mlp(const float* __restrict__ s, const float* __restrict__ dinv,
                           const float* __restrict__ W1, const float* __restrict__ b1,
                           const float* __restrict__ W2,
                           float* __restrict__ h2pre, float* __restrict__ agg2, int n) {
    int i = blockIdx.x * blockDim.x + threadIdx.x;
    if (i >= n) return;
    float sv = s[i];
    float h1[HID];
#pragma unroll
    for (int j = 0; j < HID; ++j)
        h1[j] = fmaxf(sv * W1[j] + b1[j], 0.0f);
    float d2 = dinv[i] * dinv[i];
    float h2[HID];
#pragma unroll
    for (int k = 0; k < HID; ++k) {
        float acc = 0.0f;
#pragma unroll
        for (int j = 0; j < HID; ++j)
            acc = fmaf(h1[j], W2[j * HID + k], acc);
        h2[k] = acc;
    }
    float4* hp = (float4*)(h2pre + (size_t)i * HID);
    float4* ap = (float4*)(agg2 + (size_t)i * HID);
#pragma unroll
    for (int q = 0; q < 4; ++q) {
        float4 v = make_float4(h2[q*4+0], h2[q*4+1], h2[q*4+2], h2[q*4+3]);
        hp[q] = v;
        ap[q] = make_float4(v.x * d2, v.y * d2, v.z * d2, v.w * d2);
    }
}

__global__ void f_agg_edge(const int* __restrict__ srcA, const int* __restrict__ dstA,
                           const float* __restrict__ dinv,
                           const float* __restrict__ h2pre,
                           float* __restrict__ agg2, int e) {
    int gid = blockIdx.x * blockDim.x + threadIdx.x;
    int ei = gid >> 4;
    int j  = gid & 15;
    if (ei < e) {
        int si = srcA[ei], di = dstA[ei];
        float w = dinv[si] * dinv[di];
        atomicAdd(&agg2[(size_t)di * HID + j], h2pre[(size_t)si * HID + j] * w);
    }
}

__global__ void f_out(const float* __restrict__ agg2, const float* __restrict__ b2,
                      const float* __restrict__ Wf, const float* __restrict__ bf,
                      float* __restrict__ out, int n) {
    int i = blockIdx.x * blockDim.x + threadIdx.x;
    if (i >= n) return;
    float acc = bf[0];
#pragma unroll
    for (int k = 0; k < HID; ++k) {
        float h = fmaxf(agg2[(size_t)i * HID + k] + b2[k], 0.0f);
        acc = fmaf(h, Wf[k], acc);
    }
    out[i] = tanhf(acc);
}

// ============================= launch =============================

extern "C" void kernel_launch(void* const* d_in, const int* in_sizes, int n_in,
                              void* d_out, int out_size, void* d_ws, size_t ws_size,
                              hipStream_t stream) {
    const float* x  = (const float*)d_in[0];
    const int*   ei = (const int*)d_in[1];
    const float* W1 = (const float*)d_in[2];
    const float* b1 = (const float*)d_in[3];
    const float* W2 = (const float*)d_in[4];
    const float* b2 = (const float*)d_in[5];
    const float* Wf = (const float*)d_in[6];
    const float* bf = (const float*)d_in[7];
    float* out = (float*)d_out;

    const int N = in_sizes[0];
    const int E = in_sizes[1] / 2;
    const int* srcA = ei;
    const int* dstA = ei + E;
    (void)n_in; (void)out_size;

    const int NB = (N + PMASK) >> PSHIFT;
    const int B = 256;
    int nb_n = (N + B - 1) / B;
    int nb_e = (E + B - 1) / B;
    int tiles = (E + TILE - 1) / TILE;

    // fast-path ws layout
    size_t off = 0;
    auto takeo = [&](size_t bytes) -> size_t {
        size_t p = off;
        off = (off + bytes + 255) & ~(size_t)255;
        return p;
    };
    size_t o_cntp = takeo((size_t)NB * PAD * 4);
    size_t o_curp = takeo((size_t)NB * PAD * 4);
    size_t o_bb   = takeo((size_t)NB * 4);
    size_t o_bc   = takeo((size_t)NB * 4);
    size_t o_dinv = takeo((size_t)N * 4);
    size_t o_y    = takeo((size_t)N * 4);
    size_t o_part = takeo((size_t)E * 4);
    size_t o_g    = takeo((size_t)N * HID * 4);
    size_t need = off;

    if (N <= (1 << SRCBITS) && NB <= MAXNB && ws_size >= need) {
        char* ws = (char*)d_ws;
        uint*  cntPad    = (uint*)(ws + o_cntp);
        uint*  cursorPad = (uint*)(ws + o_curp);
        uint*  bBase     = (uint*)(ws + o_bb);
        uint*  bCnt      = (uint*)(ws + o_bc);
        float* dinv      = (float*)(ws + o_dinv);
        float* y         = (float*)(ws + o_y);
        uint*  part      = (uint*)(ws + o_part);
        float* g         = (float*)(ws + o_g);

        hipMemsetAsync(cntPad, 0, (size_t)NB * PAD * 4, stream);
        hipLaunchKernelGGL(p_bcount, dim3(tiles), dim3(B), 0, stream, dstA, cntPad, E, NB);
        hipLaunchKernelGGL(p_bscan,  dim3(1), dim3(B), 0, stream, cntPad, cursorPad, bBase, bCnt, NB);
        hipLaunchKernelGGL(p_part,   dim3(tiles), dim3(B), 0, stream, srcA, dstA, cursorPad, part, E, NB);
        hipLaunchKernelGGL(p_degy,   dim3(NB), dim3(AGT), 0, stream, part, bBase, bCnt, x, dinv, y, N);
        hipLaunchKernelGGL(p_agg1,   dim3(NB), dim3(AGT), 0, stream, part, bBase, bCnt, y, dinv, W1, b1, W2, g, N);
        hipLaunchKernelGGL(p_sagg2,  dim3(NB), dim3(AGT), 0, stream, part, bBase, bCnt, g, dinv, b2, Wf, bf, out, N);
    } else {
        // fallback: known-good atomic path
        size_t foff = 0;
        auto ftake = [&](size_t bytes) -> size_t {
            size_t p = foff;
            foff = (foff + bytes + 255) & ~(size_t)255;
            return p;
        };
        char* ws = (char*)d_ws;
        float* dinv  = (float*)(ws + ftake((size_t)N * 4));
        float* s     = (float*)(ws + ftake((size_t)N * 4));
        float* h2pre = (float*)(ws + ftake((size_t)N * HID * 4));
        float* agg2  = (float*)(ws + ftake((size_t)N * HID * 4));

        long long totD = (long long)E * HID;
        int nb_d = (int)((totD + B - 1) / B);

        hipLaunchKernelGGL(f_init_deg,  dim3(nb_n), dim3(B), 0, stream, dinv, N);
        hipLaunchKernelGGL(f_deg_accum, dim3(nb_e), dim3(B), 0, stream, dstA, dinv, E);
        hipLaunchKernelGGL(f_dinv_s,    dim3(nb_n), dim3(B), 0, stream, x, dinv, s, N);
        hipLaunchKernelGGL(f_s_edge,    dim3(nb_e), dim3(B), 0, stream, srcA, dstA, x, dinv, s, E);
        hipLaunchKernelGGL(f_node_mlp,  dim3(nb_n), dim3(B), 0, stream,
                           s, dinv, W1, b1, W2, h2pre, agg2, N);
        hipLaunchKernelGGL(f_agg_edge,  dim3(nb_d), dim3(B), 0, stream,
                           srcA, dstA, dinv, h2pre, agg2, E);
        hipLaunchKernelGGL(f_out,       dim3(nb_n), dim3(B), 0, stream,
                           agg2, b2, Wf, bf, out, N);
    }
}

// Round 8
// 151.540 us; speedup vs baseline: 3.3128x; 1.0370x over previous
//
#include <hip/hip_runtime.h>
#include <math.h>

#define HID 16
typedef unsigned int uint;

#define PSHIFT 7            // 128 nodes per dst-bucket
#define PSIZE  128
#define PMASK  127
#define SRCBITS 17          // supports N <= 131072
#define SRCMASK 0x1FFFFu
#define SENT 0xFFFFFFFFu
#define PAD 16              // uints between atomic counters (64B anti-contention)
#define TILE 8192           // edges per partition tile
#define MAXNB 1024          // max dst-buckets (N<=131072)
#define AGT 1024            // threads for sort/slow kernels
#define CAP 6144            // staged-sort size (avg bucket ~4096)

// ============================= fast path =============================

// ---- pass 1: per-bucket edge counts (int4-vectorized stream) ----
__global__ void p_bcount(const int* __restrict__ dstA, uint* __restrict__ cntPad,
                         int e, int nb) {
    __shared__ uint hist[MAXNB];
    int t = threadIdx.x;
    for (int i = t; i < nb; i += 256) hist[i] = 0;
    __syncthreads();
    int base = blockIdx.x * TILE;
    int lim = min(TILE, e - base);
    const int4* d4 = (const int4*)(dstA + base);
    int n4 = lim >> 2;
    for (int k = t; k < n4; k += 256) {
        int4 d = d4[k];
        atomicAdd(&hist[((uint)d.x) >> PSHIFT], 1u);
        atomicAdd(&hist[((uint)d.y) >> PSHIFT], 1u);
        atomicAdd(&hist[((uint)d.z) >> PSHIFT], 1u);
        atomicAdd(&hist[((uint)d.w) >> PSHIFT], 1u);
    }
    for (int i = (n4 << 2) + t; i < lim; i += 256)
        atomicAdd(&hist[((uint)dstA[base + i]) >> PSHIFT], 1u);
    __syncthreads();
    for (int i = t; i < nb; i += 256) {
        uint c = hist[i];
        if (c) atomicAdd(&cntPad[i * PAD], c);
    }
}

// ---- pass 2: exclusive scan of bucket counts; init global cursors ----
__global__ void p_bscan(const uint* __restrict__ cntPad, uint* __restrict__ cursorPad,
                        uint* __restrict__ bBase, uint* __restrict__ bCnt, int nb) {
    __shared__ uint tsum[256];
    int t = threadIdx.x;
    uint loc[4]; uint s = 0;
#pragma unroll
    for (int k = 0; k < 4; ++k) {
        int i = t * 4 + k;
        uint c = (i < nb) ? cntPad[i * PAD] : 0u;
        loc[k] = s; s += c;
    }
    tsum[t] = s;
    __syncthreads();
    for (int off = 1; off < 256; off <<= 1) {
        uint v = (t >= off) ? tsum[t - off] : 0u;
        __syncthreads();
        tsum[t] += v;
        __syncthreads();
    }
    uint excl = (t == 0) ? 0u : tsum[t - 1];
#pragma unroll
    for (int k = 0; k < 4; ++k) {
        int i = t * 4 + k;
        if (i < nb) {
            uint c = cntPad[i * PAD];
            uint b = excl + loc[k];
            bBase[i] = b; bCnt[i] = c; cursorPad[i * PAD] = b;
        }
    }
}

// ---- pass 3: partition edges into dst-buckets (LDS multisplit per tile) ----
__global__ void p_part(const int* __restrict__ srcA, const int* __restrict__ dstA,
                       uint* __restrict__ cursorPad, uint* __restrict__ part,
                       int e, int nb) {
    __shared__ uint payload[TILE];      // 32 KB
    __shared__ uint hist[MAXNB];
    __shared__ uint binStart[MAXNB];
    __shared__ uint cursorL[MAXNB];
    __shared__ uint gdelta[MAXNB];
    __shared__ uint tsum[256];
    int t = threadIdx.x;
    for (int i = t; i < nb; i += 256) hist[i] = 0;
    __syncthreads();
    int base = blockIdx.x * TILE;
    int lim = min(TILE, e - base);
    const int4* s4 = (const int4*)(srcA + base);
    const int4* d4 = (const int4*)(dstA + base);
    int n4 = lim >> 2;
    // phase A: tile histogram
    for (int k = t; k < n4; k += 256) {
        int4 d = d4[k];
        atomicAdd(&hist[((uint)d.x) >> PSHIFT], 1u);
        atomicAdd(&hist[((uint)d.y) >> PSHIFT], 1u);
        atomicAdd(&hist[((uint)d.z) >> PSHIFT], 1u);
        atomicAdd(&hist[((uint)d.w) >> PSHIFT], 1u);
    }
    for (int i = (n4 << 2) + t; i < lim; i += 256)
        atomicAdd(&hist[((uint)dstA[base + i]) >> PSHIFT], 1u);
    __syncthreads();
    // phase B: scan -> binStart; reserve global space per bucket
    uint loc[4]; uint s = 0;
#pragma unroll
    for (int k = 0; k < 4; ++k) {
        int i = t * 4 + k;
        uint c = (i < nb) ? hist[i] : 0u;
        loc[k] = s; s += c;
    }
    tsum[t] = s;
    __syncthreads();
    for (int off = 1; off < 256; off <<= 1) {
        uint v = (t >= off) ? tsum[t - off] : 0u;
        __syncthreads();
        tsum[t] += v;
        __syncthreads();
    }
    uint excl = (t == 0) ? 0u : tsum[t - 1];
#pragma unroll
    for (int k = 0; k < 4; ++k) {
        int i = t * 4 + k;
        if (i < nb) {
            uint bs = excl + loc[k];
            binStart[i] = bs; cursorL[i] = bs;
            uint c = hist[i];
            if (c) gdelta[i] = atomicAdd(&cursorPad[i * PAD], c) - bs;
        }
    }
    __syncthreads();
    // phase C: scatter packed words into LDS, grouped by bucket
    for (int k = t; k < n4; k += 256) {
        int4 dd = d4[k]; int4 ss = s4[k];
#pragma unroll
        for (int q = 0; q < 4; ++q) {
            uint d = (uint)((q == 0) ? dd.x : (q == 1) ? dd.y : (q == 2) ? dd.z : dd.w);
            uint sv = (uint)((q == 0) ? ss.x : (q == 1) ? ss.y : (q == 2) ? ss.z : ss.w);
            uint w = ((d & PMASK) << SRCBITS) | sv;
            uint pos = atomicAdd(&cursorL[d >> PSHIFT], 1u);
            payload[pos] = w;
        }
    }
    for (int i = (n4 << 2) + t; i < lim; i += 256) {
        uint d = (uint)dstA[base + i];
        uint w = ((d & PMASK) << SRCBITS) | (uint)srcA[base + i];
        uint pos = atomicAdd(&cursorL[d >> PSHIFT], 1u);
        payload[pos] = w;
    }
    __syncthreads();
    // phase D: flush contiguous runs to global (16-lane groups per run)
    int grp = t >> 4, lane16 = t & 15;
    for (int bk = grp; bk < nb; bk += 16) {
        uint c = hist[bk];
        if (!c) continue;
        uint st = binStart[bk];
        uint gd = gdelta[bk];
        for (uint i = lane16; i < c; i += 16)
            part[gd + st + i] = payload[st + i];
    }
}

// ---- pass 4: per-bucket counting sort (in place) + degree -> dinv, y ----
__global__ __launch_bounds__(AGT)
void p_sort(uint* __restrict__ part, const uint* __restrict__ bBase,
            const uint* __restrict__ bCnt, const float* __restrict__ x,
            uint* __restrict__ rowEnd, uint* __restrict__ oversz,
            float* __restrict__ dinv, float* __restrict__ y, int n) {
    __shared__ uint lds[2 * CAP];       // 48 KB
    __shared__ uint hist[PSIZE];
    __shared__ uint cursor[PSIZE];
    int b = blockIdx.x, t = threadIdx.x;
    uint base = bBase[b], cnt = bCnt[b];
    if (t < PSIZE) hist[t] = 0;
    if (t == 0) oversz[b] = (cnt > 2 * CAP) ? 1u : 0u;
    __syncthreads();
    bool fits = (cnt <= 2 * CAP);
    if (fits) {
        for (uint i = t; i < cnt; i += AGT) {
            uint w = part[base + i];
            lds[i] = w;
            atomicAdd(&hist[w >> SRCBITS], 1u);
        }
    } else {
        for (uint i = t; i < cnt; i += AGT)
            atomicAdd(&hist[part[base + i] >> SRCBITS], 1u);
    }
    __syncthreads();
    uint myc = (t < PSIZE) ? hist[t] : 0u;
    for (int off = 1; off < PSIZE; off <<= 1) {
        uint v = 0;
        if (t < PSIZE && t >= off) v = hist[t - off];
        __syncthreads();
        if (t < PSIZE) hist[t] += v;
        __syncthreads();
    }
    if (t < PSIZE) cursor[t] = hist[t] - myc;   // exclusive start
    __syncthreads();
    if (fits) {
        if (cnt <= CAP) {
            // sort into LDS, then coalesced write-back
            for (uint i = t; i < cnt; i += AGT) {
                uint w = lds[i];
                uint pos = atomicAdd(&cursor[w >> SRCBITS], 1u);
                lds[CAP + pos] = w & SRCMASK;
            }
            __syncthreads();
            for (uint i = t; i < cnt; i += AGT)
                part[base + i] = lds[CAP + i];
        } else {
            // all reads already staged in LDS -> direct scattered write-back is safe
            for (uint i = t; i < cnt; i += AGT) {
                uint w = lds[i];
                uint pos = atomicAdd(&cursor[w >> SRCBITS], 1u);
                part[base + pos] = w & SRCMASK;
            }
        }
    }
    if (t < PSIZE) {
        int node = b * PSIZE + t;
        if (node < n) {
            rowEnd[node] = fits ? (base + hist[t]) : SENT;
            float d = rsqrtf((float)(myc + 1u));   // +1 self-loop
            dinv[node] = d;
            y[node] = x[node] * d;
        }
    }
}

// ---- pass 5: layer-1 segment gather (1 thread/node) + fused MLP -> g ----
__global__ void p_g1mlp(const uint* __restrict__ part, const uint* __restrict__ rowEnd,
                        const uint* __restrict__ bBase,
                        const float* __restrict__ y, const float* __restrict__ dinv,
                        const float* __restrict__ W1, const float* __restrict__ b1,
                        const float* __restrict__ W2,
                        float* __restrict__ g, int n) {
    int i = blockIdx.x * blockDim.x + threadIdx.x;
    if (i >= n) return;
    uint en = rowEnd[i];
    if (en == SENT) return;             // oversize bucket: p_slow1 handles
    uint st = (i & PMASK) ? rowEnd[i - 1] : bBase[i >> PSHIFT];
    float tsum = 0.0f;
    uint e = st;
    for (; e + 4 <= en; e += 4)
        tsum += y[part[e]] + y[part[e + 1]] + y[part[e + 2]] + y[part[e + 3]];
    for (; e < en; ++e) tsum += y[part[e]];
    float d = dinv[i];
    float sv = d * (tsum + y[i]);       // self-loop: x*dinv^2 = dinv*y
    float h1[HID], h2[HID];
#pragma unroll
    for (int j = 0; j < HID; ++j)
        h1[j] = fmaxf(sv * W1[j] + b1[j], 0.0f);
#pragma unroll
    for (int k = 0; k < HID; ++k) {
        float a = 0.0f;
#pragma unroll
        for (int j = 0; j < HID; ++j)
            a = fmaf(h1[j], W2[j * HID + k], a);
        h2[k] = a * d;
    }
    float4* gp = (float4*)(g + (size_t)i * HID);
#pragma unroll
    for (int q = 0; q < 4; ++q)
        gp[q] = make_float4(h2[q*4+0], h2[q*4+1], h2[q*4+2], h2[q*4+3]);
}

// ---- pass 6: layer-2 segment gather (16 lanes/node) + fused epilogue ----
__global__ void p_g2out(const uint* __restrict__ part, const uint* __restrict__ rowEnd,
                        const uint* __restrict__ bBase,
                        const float* __restrict__ g, const float* __restrict__ dinv,
                        const float* __restrict__ b2, const float* __restrict__ Wf,
                        const float* __restrict__ bf,
                        float* __restrict__ out, int n) {
    int gid = blockIdx.x * blockDim.x + threadIdx.x;
    int node = gid >> 4, lane = gid & 15;
    if (node >= n) return;
    uint en = rowEnd[node];
    if (en == SENT) return;             // oversize bucket: p_slow2 handles
    uint st = (node & PMASK) ? rowEnd[node - 1] : bBase[node >> PSHIFT];
    float a = 0.0f;
    uint e = st;
    for (; e + 4 <= en; e += 4) {
        uint s0 = part[e], s1 = part[e + 1], s2 = part[e + 2], s3 = part[e + 3];
        a += g[(size_t)s0 * HID + lane] + g[(size_t)s1 * HID + lane]
           + g[(size_t)s2 * HID + lane] + g[(size_t)s3 * HID + lane];
    }
    for (; e < en; ++e) a += g[(size_t)part[e] * HID + lane];
    float d = dinv[node];
    float h = fmaxf(d * (a + g[(size_t)node * HID + lane]) + b2[lane], 0.0f);
    float v = h * Wf[lane];
#pragma unroll
    for (int m = 8; m >= 1; m >>= 1)
        v += __shfl_xor(v, m, 16);
    if (lane == 0) out[node] = tanhf(v + bf[0]);
}

// ---- rare-path kernels: oversize (unsorted) buckets, LDS-atomic accumulation ----
__global__ __launch_bounds__(AGT)
void p_slow1(const uint* __restrict__ part, const uint* __restrict__ bBase,
             const uint* __restrict__ bCnt, const uint* __restrict__ oversz,
             const float* __restrict__ y, const float* __restrict__ dinv,
             const float* __restrict__ W1, const float* __restrict__ b1,
             const float* __restrict__ W2, float* __restrict__ g, int n) {
    int b = blockIdx.x;
    if (!oversz[b]) return;
    __shared__ float acc[PSIZE];
    int t = threadIdx.x;
    if (t < PSIZE) acc[t] = 0.0f;
    __syncthreads();
    uint base = bBase[b], cnt = bCnt[b];
    for (uint i = base + t; i < base + cnt; i += AGT) {
        uint w = part[i];
        atomicAdd(&acc[w >> SRCBITS], y[w & SRCMASK]);
    }
    __syncthreads();
    if (t < PSIZE) {
        int node = b * PSIZE + t;
        if (node < n) {
            float d = dinv[node];
            float sv = d * (acc[t] + y[node]);
            float h1[HID], h2[HID];
#pragma unroll
            for (int j = 0; j < HID; ++j)
                h1[j] = fmaxf(sv * W1[j] + b1[j], 0.0f);
#pragma unroll
            for (int k = 0; k < HID; ++k) {
                float a = 0.0f;
#pragma unroll
                for (int j = 0; j < HID; ++j)
                    a = fmaf(h1[j], W2[j * HID + k], a);
                h2[k] = a * d;
            }
            float4* gp = (float4*)(g + (size_t)node * HID);
#pragma unroll
            for (int q = 0; q < 4; ++q)
                gp[q] = make_float4(h2[q*4+0], h2[q*4+1], h2[q*4+2], h2[q*4+3]);
        }
    }
}

__global__ __launch_bounds__(AGT)
void p_slow2(const uint* __restrict__ part, const uint* __restrict__ bBase,
             const uint* __restrict__ bCnt, const uint* __restrict__ oversz,
             const float* __restrict__ g, const float* __restrict__ dinv,
             const float* __restrict__ b2, const float* __restrict__ Wf,
             const float* __restrict__ bf, float* __restrict__ out, int n) {
    int b = blockIdx.x;
    if (!oversz[b]) return;
    __shared__ float acc[PSIZE][HID + 1];
    int t = threadIdx.x;
    if (t < PSIZE * 4) {
        int r = t >> 2, q = t & 3;
        int node = b * PSIZE + r;
        if (node < n) {
            float4 v = *(const float4*)(g + (size_t)node * HID + 4 * q);
            acc[r][q*4+0] = v.x; acc[r][q*4+1] = v.y;
            acc[r][q*4+2] = v.z; acc[r][q*4+3] = v.w;
        } else {
            acc[r][q*4+0] = 0.0f; acc[r][q*4+1] = 0.0f;
            acc[r][q*4+2] = 0.0f; acc[r][q*4+3] = 0.0f;
        }
    }
    __syncthreads();
    uint base = bBase[b], cnt = bCnt[b];
    int gi = t >> 2, sub = t & 3;
    for (uint i = base + gi; i < base + cnt; i += AGT / 4) {
        uint w = part[i];
        uint src = w & SRCMASK;
        uint dl = w >> SRCBITS;
        float4 v = *(const float4*)(g + (size_t)src * HID + 4 * sub);
        atomicAdd(&acc[dl][sub*4+0], v.x);
        atomicAdd(&acc[dl][sub*4+1], v.y);
        atomicAdd(&acc[dl][sub*4+2], v.z);
        atomicAdd(&acc[dl][sub*4+3], v.w);
    }
    __syncthreads();
    if (t < PSIZE) {
        int node = b * PSIZE + t;
        if (node < n) {
            float d = dinv[node];
            float o = bf[0];
#pragma unroll
            for (int j = 0; j < HID; ++j) {
                float h = fmaxf(fmaf(d, acc[t][j], b2[j]), 0.0f);
                o = fmaf(h, Wf[j], o);
            }
            out[node] = tanhf(o);
        }
    }
}

// ============================= fallback (atomic) path =============================

__global__ void f_init_deg(float* deg, int n) {
    int i = blockIdx.x * blockDim.x + threadIdx.x;
    if (i < n) deg[i] = 1.0f;
}

__global__ void f_deg_accum(const int* __restrict__ dstA, float* deg, int e) {
    int i = blockIdx.x * blockDim.x + threadIdx.x;
    if (i < e) atomicAdd(&deg[dstA[i]], 1.0f);
}

__global__ void f_dinv_s(const float* __restrict__ x, float* deg_dinv, float* s, int n) {
    int i = blockIdx.x * blockDim.x + threadIdx.x;
    if (i < n) {
        float d = rsqrtf(deg_dinv[i]);
        deg_dinv[i] = d;
        s[i] = x[i] * d * d;
    }
}

__global__ void f_s_edge(const int* __restrict__ srcA, const int* __restrict__ dstA,
                         const float* __restrict__ x, const float* __restrict__ dinv,
                         float* s, int e) {
    int i = blockIdx.x * blockDim.x + threadIdx.x;
    if (i < e) {
        int si = srcA[i], di = dstA[i];
        atomicAdd(&s[di], x[si] * dinv[si] * dinv[di]);
    }
}

__global__ void f_node_mlp(const float* __restrict__ s, const float* __restrict__ dinv,
                           const float* __restrict__ W1, const float* __restrict__ b1,
                           const float* __restrict__ W2,
                           float* __restrict__ h2pre, float* __restrict__ agg2, int n) {
    int i = blockIdx.x * blockDim.x + threadIdx.x;
    if (i >= n) return;
    float sv = s[i];
    float h1[HID];
#pragma unroll
    for (int j = 0; j < HID; ++j)
        h1[j] = fmaxf(sv * W1[j] + b1[j], 0.0f);
    float d2 = dinv[i] * dinv[i];
    float h2[HID];
#pragma unroll
    for (int k = 0; k < HID; ++k) {
        float acc = 0.0f;
#pragma unroll
        for (int j = 0; j < HID; ++j)
            acc = fmaf(h1[j], W2[j * HID + k], acc);
        h2[k] = acc;
    }
    float4* hp = (float4*)(h2pre + (size_t)i * HID);
    float4* ap = (float4*)(agg2 + (size_t)i * HID);
#pragma unroll
    for (int q = 0; q < 4; ++q) {
        float4 v = make_float4(h2[q*4+0], h2[q*4+1], h2[q*4+2], h2[q*4+3]);
        hp[q] = v;
        ap[q] = make_float4(v.x * d2, v.y * d2, v.z * d2, v.w * d2);
    }
}

__global__ void f_agg_edge(const int* __restrict__ srcA, const int* __restrict__ dstA,
                           const float* __restrict__ dinv,
                           const float* __restrict__ h2pre,
                           float* __restrict__ agg2, int e) {
    int gid = blockIdx.x * blockDim.x + threadIdx.x;
    int ei = gid >> 4;
    int j  = gid & 15;
    if (ei < e) {
        int si = srcA[ei], di = dstA[ei];
        float w = dinv[si] * dinv[di];
        atomicAdd(&agg2[(size_t)di * HID + j], h2pre[(size_t)si * HID + j] * w);
    }
}

__global__ void f_out(const float* __restrict__ agg2, const float* __restrict__ b2,
                      const float* __restrict__ Wf, const float* __restrict__ bf,
                      float* __restrict__ out, int n) {
    int i = blockIdx.x * blockDim.x + threadIdx.x;
    if (i >= n) return;
    float acc = bf[0];
#pragma unroll
    for (int k = 0; k < HID; ++k) {
        float h = fmaxf(agg2[(size_t)i * HID + k] + b2[k], 0.0f);
        acc = fmaf(h, Wf[k], acc);
    }
    out[i] = tanhf(acc);
}

// ============================= launch =============================

extern "C" void kernel_launch(void* const* d_in, const int* in_sizes, int n_in,
                              void* d_out, int out_size, void* d_ws, size_t ws_size,
                              hipStream_t stream) {
    const float* x  = (const float*)d_in[0];
    const int*   ei = (const int*)d_in[1];
    const float* W1 = (const float*)d_in[2];
    const float* b1 = (const float*)d_in[3];
    const float* W2 = (const float*)d_in[4];
    const float* b2 = (const float*)d_in[5];
    const float* Wf = (const float*)d_in[6];
    const float* bf = (const float*)d_in[7];
    float* out = (float*)d_out;

    const int N = in_sizes[0];
    const int E = in_sizes[1] / 2;
    const int* srcA = ei;
    const int* dstA = ei + E;
    (void)n_in; (void)out_size;

    const int NB = (N + PMASK) >> PSHIFT;
    const int B = 256;
    int nb_n = (N + B - 1) / B;
    int nb_e = (E + B - 1) / B;
    int tiles = (E + TILE - 1) / TILE;

    // fast-path ws layout
    size_t off = 0;
    auto takeo = [&](size_t bytes) -> size_t {
        size_t p = off;
        off = (off + bytes + 255) & ~(size_t)255;
        return p;
    };
    size_t o_cntp = takeo((size_t)NB * PAD * 4);
    size_t o_curp = takeo((size_t)NB * PAD * 4);
    size_t o_bb   = takeo((size_t)NB * 4);
    size_t o_bc   = takeo((size_t)NB * 4);
    size_t o_ovs  = takeo((size_t)NB * 4);
    size_t o_dinv = takeo((size_t)N * 4);
    size_t o_y    = takeo((size_t)N * 4);
    size_t o_re   = takeo((size_t)N * 4);
    size_t o_part = takeo((size_t)E * 4);
    size_t o_g    = takeo((size_t)N * HID * 4);
    size_t need = off;

    if (N <= (1 << SRCBITS) && NB <= MAXNB && ws_size >= need) {
        char* ws = (char*)d_ws;
        uint*  cntPad    = (uint*)(ws + o_cntp);
        uint*  cursorPad = (uint*)(ws + o_curp);
        uint*  bBase     = (uint*)(ws + o_bb);
        uint*  bCnt      = (uint*)(ws + o_bc);
        uint*  oversz    = (uint*)(ws + o_ovs);
        float* dinv      = (float*)(ws + o_dinv);
        float* y         = (float*)(ws + o_y);
        uint*  rowEnd    = (uint*)(ws + o_re);
        uint*  part      = (uint*)(ws + o_part);
        float* g         = (float*)(ws + o_g);

        int nb_g2 = (int)(((size_t)N * 16 + B - 1) / B);

        hipMemsetAsync(cntPad, 0, (size_t)NB * PAD * 4, stream);
        hipLaunchKernelGGL(p_bcount, dim3(tiles), dim3(B), 0, stream, dstA, cntPad, E, NB);
        hipLaunchKernelGGL(p_bscan,  dim3(1), dim3(B), 0, stream, cntPad, cursorPad, bBase, bCnt, NB);
        hipLaunchKernelGGL(p_part,   dim3(tiles), dim3(B), 0, stream, srcA, dstA, cursorPad, part, E, NB);
        hipLaunchKernelGGL(p_sort,   dim3(NB), dim3(AGT), 0, stream,
                           part, bBase, bCnt, x, rowEnd, oversz, dinv, y, N);
        hipLaunchKernelGGL(p_g1mlp,  dim3(nb_n), dim3(B), 0, stream,
                           part, rowEnd, bBase, y, dinv, W1, b1, W2, g, N);
        hipLaunchKernelGGL(p_slow1,  dim3(NB), dim3(AGT), 0, stream,
                           part, bBase, bCnt, oversz, y, dinv, W1, b1, W2, g, N);
        hipLaunchKernelGGL(p_g2out,  dim3(nb_g2), dim3(B), 0, stream,
                           part, rowEnd, bBase, g, dinv, b2, Wf, bf, out, N);
        hipLaunchKernelGGL(p_slow2,  dim3(NB), dim3(AGT), 0, stream,
                           part, bBase, bCnt, oversz, g, dinv, b2, Wf, bf, out, N);
    } else {
        // fallback: known-good atomic path
        size_t foff = 0;
        auto ftake = [&](size_t bytes) -> size_t {
            size_t p = foff;
            foff = (foff + bytes + 255) & ~(size_t)255;
            return p;
        };
        char* ws = (char*)d_ws;
        float* dinv  = (float*)(ws + ftake((size_t)N * 4));
        float* s     = (float*)(ws + ftake((size_t)N * 4));
        float* h2pre = (float*)(ws + ftake((size_t)N * HID * 4));
        float* agg2  = (float*)(ws + ftake((size_t)N * HID * 4));

        long long totD = (long long)E * HID;
        int nb_d = (int)((totD + B - 1) / B);

        hipLaunchKernelGGL(f_init_deg,  dim3(nb_n), dim3(B), 0, stream, dinv, N);
        hipLaunchKernelGGL(f_deg_accum, dim3(nb_e), dim3(B), 0, stream, dstA, dinv, E);
        hipLaunchKernelGGL(f_dinv_s,    dim3(nb_n), dim3(B), 0, stream, x, dinv, s, N);
        hipLaunchKernelGGL(f_s_edge,    dim3(nb_e), dim3(B), 0, stream, srcA, dstA, x, dinv, s, E);
        hipLaunchKernelGGL(f_node_mlp,  dim3(nb_n), dim3(B), 0, stream,
                           s, dinv, W1, b1, W2, h2pre, agg2, N);
        hipLaunchKernelGGL(f_agg_edge,  dim3(nb_d), dim3(B), 0, stream,
                           srcA, dstA, dinv, h2pre, agg2, E);
        hipLaunchKernelGGL(f_out,       dim3(nb_n), dim3(B), 0, stream,
                           agg2, b2, Wf, bf, out, N);
    }
}